// Round 1
// baseline (10988.356 us; speedup 1.0000x reference)
//
#include <hip/hip_runtime.h>

#define NN 100000
#define NE 3200000
#define FD 128

// ---------------------------------------------------------------------------
// Fused triple GEMM:  OUT = X@H0, V = X@H1, T2 = X@H2   (all fp32 vector ALU)
// 256 threads, tile = 128 rows x 128 cols, K = 128 staged in LDS.
// Thread (tx = tid&15, ty = tid>>4) owns rows {ty + 16*i} (i<8) and cols
// {tx*4..tx*4+3, 64+tx*4..}. Stride-16 row ownership keeps the b128 X reads
// bank-conflict-free with the +4-float row pad (132).
// ---------------------------------------------------------------------------
__global__ __launch_bounds__(256, 1)
void gemm3_kernel(const float* __restrict__ X, const float* __restrict__ H,
                  float* __restrict__ OUT, float* __restrict__ V,
                  float* __restrict__ T2) {
    __shared__ float Xs[128][132];   // 67.6 KB (pad 4 floats: 16B-aligned rows)
    __shared__ float Hs[128][128];   // 64 KB
    const int tid  = threadIdx.x;
    const int row0 = blockIdx.x * 128;

    // --- load X tile (zero-fill OOB rows). 16384 floats / 256 thr = 16 float4
    for (int it = 0; it < 16; ++it) {
        int idx = it * 1024 + tid * 4;      // flat float index in 128x128 tile
        int r = idx >> 7, c = idx & 127;
        int gr = row0 + r;
        float4 v = make_float4(0.f, 0.f, 0.f, 0.f);
        if (gr < NN) v = *reinterpret_cast<const float4*>(X + gr * FD + c);
        *reinterpret_cast<float4*>(&Xs[r][c]) = v;
    }

    const int tx = tid & 15;
    const int ty = tid >> 4;

    #pragma unroll
    for (int k = 0; k < 3; ++k) {
        __syncthreads();   // Hs readers of previous k done; also covers Xs fill
        for (int it = 0; it < 16; ++it) {
            int idx = it * 1024 + tid * 4;
            *(reinterpret_cast<float4*>(&Hs[0][0] + idx)) =
                *reinterpret_cast<const float4*>(H + k * (FD * FD) + idx);
        }
        __syncthreads();

        float acc[8][8];
        #pragma unroll
        for (int i = 0; i < 8; ++i)
            #pragma unroll
            for (int j = 0; j < 8; ++j) acc[i][j] = 0.f;

        for (int kk = 0; kk < FD; kk += 4) {
            // X: one float4 per owned row (rows ty + 16*i)
            float4 xq[8];
            #pragma unroll
            for (int i = 0; i < 8; ++i)
                xq[i] = *reinterpret_cast<const float4*>(&Xs[ty + 16 * i][kk]);
            #pragma unroll
            for (int s = 0; s < 4; ++s) {
                float4 h0 = *reinterpret_cast<const float4*>(&Hs[kk + s][tx * 4]);
                float4 h1 = *reinterpret_cast<const float4*>(&Hs[kk + s][64 + tx * 4]);
                #pragma unroll
                for (int i = 0; i < 8; ++i) {
                    float xv = (s == 0) ? xq[i].x : (s == 1) ? xq[i].y
                             : (s == 2) ? xq[i].z : xq[i].w;
                    acc[i][0] += xv * h0.x; acc[i][1] += xv * h0.y;
                    acc[i][2] += xv * h0.z; acc[i][3] += xv * h0.w;
                    acc[i][4] += xv * h1.x; acc[i][5] += xv * h1.y;
                    acc[i][6] += xv * h1.z; acc[i][7] += xv * h1.w;
                }
            }
        }

        float* dst = (k == 0) ? OUT : (k == 1) ? V : T2;
        #pragma unroll
        for (int i = 0; i < 8; ++i) {
            int gr = row0 + ty + 16 * i;
            if (gr < NN) {
                float4 a = make_float4(acc[i][0], acc[i][1], acc[i][2], acc[i][3]);
                float4 b = make_float4(acc[i][4], acc[i][5], acc[i][6], acc[i][7]);
                *reinterpret_cast<float4*>(dst + (size_t)gr * FD + tx * 4)      = a;
                *reinterpret_cast<float4*>(dst + (size_t)gr * FD + 64 + tx * 4) = b;
            }
        }
    }
}

// ---------------------------------------------------------------------------
// SpMM scatter-add:  dst[rows[e]] += vals[e] * src[cols[e]]   (dst pre-filled)
// One thread = (edge, 4 consecutive features). Wave = 2 edges -> coalesced
// 512B gathers, broadcast edge-meta loads, 4 fp32 global atomics per thread.
// ---------------------------------------------------------------------------
__global__ __launch_bounds__(256)
void spmm_atomic(const int* __restrict__ rows, const int* __restrict__ cols,
                 const float* __restrict__ vals, const float* __restrict__ src,
                 float* __restrict__ dst) {
    const int total  = NE * 32;                 // (edge, float4) items
    const int stride = gridDim.x * blockDim.x;  // multiple of 32
    for (int gid = blockIdx.x * blockDim.x + threadIdx.x; gid < total;
         gid += stride) {
        int e = gid >> 5;
        int q = (gid & 31) << 2;               // feature offset 0..124
        int r = rows[e];
        int c = cols[e];
        float v = vals[e];
        float4 s = *reinterpret_cast<const float4*>(src + (size_t)c * FD + q);
        float* d = dst + (size_t)r * FD + q;
        atomicAdd(d + 0, v * s.x);
        atomicAdd(d + 1, v * s.y);
        atomicAdd(d + 2, v * s.z);
        atomicAdd(d + 3, v * s.w);
    }
}

extern "C" void kernel_launch(void* const* d_in, const int* in_sizes, int n_in,
                              void* d_out, int out_size, void* d_ws, size_t ws_size,
                              hipStream_t stream) {
    const int*   edge_rows = (const int*)d_in[0];
    const int*   edge_cols = (const int*)d_in[1];
    const float* edge_vals = (const float*)d_in[2];
    const float* x         = (const float*)d_in[3];
    const float* H         = (const float*)d_in[4];
    float*       out       = (float*)d_out;

    float* T2 = (float*)d_ws;                       // [NN, FD] 51.2 MB
    float* V  = T2 + (size_t)NN * FD;               // [NN, FD] 51.2 MB

    // OUT = X@H0, V = X@H1, T2 = X@H2
    const int gemm_blocks = (NN + 127) / 128;       // 782
    gemm3_kernel<<<gemm_blocks, 256, 0, stream>>>(x, H, out, V, T2);

    // V += A @ T2
    spmm_atomic<<<16384, 256, 0, stream>>>(edge_rows, edge_cols, edge_vals, T2, V);

    // OUT += A @ V
    spmm_atomic<<<16384, 256, 0, stream>>>(edge_rows, edge_cols, edge_vals, V, out);
}

// Round 2
// 1360.260 us; speedup vs baseline: 8.0781x; 8.0781x over previous
//
#include <hip/hip_runtime.h>

#define NN 100000
#define NE 3200000
#define FD 128

// ---------------------------------------------------------------------------
// Fused triple GEMM:  OUT = X@H0, V = X@H1, T2 = X@H2   (fp32 vector ALU)
// ---------------------------------------------------------------------------
__global__ __launch_bounds__(256, 1)
void gemm3_kernel(const float* __restrict__ X, const float* __restrict__ H,
                  float* __restrict__ OUT, float* __restrict__ V,
                  float* __restrict__ T2) {
    __shared__ float Xs[128][132];
    __shared__ float Hs[128][128];
    const int tid  = threadIdx.x;
    const int row0 = blockIdx.x * 128;

    for (int it = 0; it < 16; ++it) {
        int idx = it * 1024 + tid * 4;
        int r = idx >> 7, c = idx & 127;
        int gr = row0 + r;
        float4 v = make_float4(0.f, 0.f, 0.f, 0.f);
        if (gr < NN) v = *reinterpret_cast<const float4*>(X + gr * FD + c);
        *reinterpret_cast<float4*>(&Xs[r][c]) = v;
    }

    const int tx = tid & 15;
    const int ty = tid >> 4;

    #pragma unroll
    for (int k = 0; k < 3; ++k) {
        __syncthreads();
        for (int it = 0; it < 16; ++it) {
            int idx = it * 1024 + tid * 4;
            *(reinterpret_cast<float4*>(&Hs[0][0] + idx)) =
                *reinterpret_cast<const float4*>(H + k * (FD * FD) + idx);
        }
        __syncthreads();

        float acc[8][8];
        #pragma unroll
        for (int i = 0; i < 8; ++i)
            #pragma unroll
            for (int j = 0; j < 8; ++j) acc[i][j] = 0.f;

        for (int kk = 0; kk < FD; kk += 4) {
            float4 xq[8];
            #pragma unroll
            for (int i = 0; i < 8; ++i)
                xq[i] = *reinterpret_cast<const float4*>(&Xs[ty + 16 * i][kk]);
            #pragma unroll
            for (int s = 0; s < 4; ++s) {
                float4 h0 = *reinterpret_cast<const float4*>(&Hs[kk + s][tx * 4]);
                float4 h1 = *reinterpret_cast<const float4*>(&Hs[kk + s][64 + tx * 4]);
                #pragma unroll
                for (int i = 0; i < 8; ++i) {
                    float xv = (s == 0) ? xq[i].x : (s == 1) ? xq[i].y
                             : (s == 2) ? xq[i].z : xq[i].w;
                    acc[i][0] += xv * h0.x; acc[i][1] += xv * h0.y;
                    acc[i][2] += xv * h0.z; acc[i][3] += xv * h0.w;
                    acc[i][4] += xv * h1.x; acc[i][5] += xv * h1.y;
                    acc[i][6] += xv * h1.z; acc[i][7] += xv * h1.w;
                }
            }
        }

        float* dst = (k == 0) ? OUT : (k == 1) ? V : T2;
        #pragma unroll
        for (int i = 0; i < 8; ++i) {
            int gr = row0 + ty + 16 * i;
            if (gr < NN) {
                float4 a = make_float4(acc[i][0], acc[i][1], acc[i][2], acc[i][3]);
                float4 b = make_float4(acc[i][4], acc[i][5], acc[i][6], acc[i][7]);
                *reinterpret_cast<float4*>(dst + (size_t)gr * FD + tx * 4)      = a;
                *reinterpret_cast<float4*>(dst + (size_t)gr * FD + 64 + tx * 4) = b;
            }
        }
    }
}

// ---------------------------------------------------------------------------
// CSR build: zero counts -> histogram -> single-block scan -> scatter pack
// ---------------------------------------------------------------------------
__global__ __launch_bounds__(256)
void zero_counts(int* __restrict__ counts) {
    int i = blockIdx.x * blockDim.x + threadIdx.x;
    if (i < NN) counts[i] = 0;
}

__global__ __launch_bounds__(256)
void hist_kernel(const int* __restrict__ rows, int* __restrict__ counts) {
    int stride = gridDim.x * blockDim.x;
    for (int e = blockIdx.x * blockDim.x + threadIdx.x; e < NE; e += stride)
        atomicAdd(&counts[rows[e]], 1);
}

__global__ __launch_bounds__(1024)
void scan_kernel(const int* __restrict__ counts, int* __restrict__ row_ptr,
                 int* __restrict__ cursor) {
    __shared__ int ssum[1024];
    const int tid   = threadIdx.x;
    const int chunk = (NN + 1023) / 1024;   // 98
    const int base  = tid * chunk;
    const int lim   = (base + chunk < NN) ? base + chunk : NN;

    int s = 0;
    for (int i = base; i < lim; ++i) s += counts[i];
    ssum[tid] = s;
    __syncthreads();
    for (int off = 1; off < 1024; off <<= 1) {   // inclusive Hillis-Steele
        int t = (tid >= off) ? ssum[tid - off] : 0;
        __syncthreads();
        ssum[tid] += t;
        __syncthreads();
    }
    int run = ssum[tid] - s;                      // exclusive prefix
    for (int i = base; i < lim; ++i) {
        row_ptr[i] = run;
        cursor[i]  = run;
        run += counts[i];
    }
    if (tid == 1023) row_ptr[NN] = ssum[1023];
}

__global__ __launch_bounds__(256)
void scatter_kernel(const int* __restrict__ rows, const int* __restrict__ cols,
                    const float* __restrict__ vals, int* __restrict__ cursor,
                    int2* __restrict__ pack) {
    int stride = gridDim.x * blockDim.x;
    for (int e = blockIdx.x * blockDim.x + threadIdx.x; e < NE; e += stride) {
        int r   = rows[e];
        int pos = atomicAdd(&cursor[r], 1);
        pack[pos] = make_int2(cols[e], __float_as_int(vals[e]));
    }
}

// ---------------------------------------------------------------------------
// CSR SpMM:  dst[r] += sum_e val_e * src[col_e]   — one wave per dest row,
// lane owns 2 features (float2), register accumulate, no atomics.
// ---------------------------------------------------------------------------
__global__ __launch_bounds__(256)
void spmm_csr(const int* __restrict__ row_ptr, const int2* __restrict__ pack,
              const float* __restrict__ src, float* __restrict__ dst) {
    const int lane = threadIdx.x & 63;
    const int row  = (blockIdx.x * blockDim.x + threadIdx.x) >> 6;
    if (row >= NN) return;

    const int beg = row_ptr[row];
    const int end = row_ptr[row + 1];

    float2 acc = *reinterpret_cast<const float2*>(dst + (size_t)row * FD + lane * 2);

    int e = beg;
    for (; e + 1 < end; e += 2) {           // unroll-2: two gathers in flight
        int2 p0 = pack[e];
        int2 p1 = pack[e + 1];
        float v0 = __int_as_float(p0.y);
        float v1 = __int_as_float(p1.y);
        float2 s0 = *reinterpret_cast<const float2*>(src + (size_t)p0.x * FD + lane * 2);
        float2 s1 = *reinterpret_cast<const float2*>(src + (size_t)p1.x * FD + lane * 2);
        acc.x += v0 * s0.x + v1 * s1.x;
        acc.y += v0 * s0.y + v1 * s1.y;
    }
    if (e < end) {
        int2 p = pack[e];
        float v = __int_as_float(p.y);
        float2 s = *reinterpret_cast<const float2*>(src + (size_t)p.x * FD + lane * 2);
        acc.x += v * s.x;
        acc.y += v * s.y;
    }
    *reinterpret_cast<float2*>(dst + (size_t)row * FD + lane * 2) = acc;
}

// Fallback (ws too small): atomic scatter SpMM
__global__ __launch_bounds__(256)
void spmm_atomic(const int* __restrict__ rows, const int* __restrict__ cols,
                 const float* __restrict__ vals, const float* __restrict__ src,
                 float* __restrict__ dst) {
    const int total  = NE * 32;
    const int stride = gridDim.x * blockDim.x;
    for (int gid = blockIdx.x * blockDim.x + threadIdx.x; gid < total;
         gid += stride) {
        int e = gid >> 5;
        int q = (gid & 31) << 2;
        int r = rows[e];
        int c = cols[e];
        float v = vals[e];
        float4 s = *reinterpret_cast<const float4*>(src + (size_t)c * FD + q);
        float* d = dst + (size_t)r * FD + q;
        atomicAdd(d + 0, v * s.x);
        atomicAdd(d + 1, v * s.y);
        atomicAdd(d + 2, v * s.z);
        atomicAdd(d + 3, v * s.w);
    }
}

extern "C" void kernel_launch(void* const* d_in, const int* in_sizes, int n_in,
                              void* d_out, int out_size, void* d_ws, size_t ws_size,
                              hipStream_t stream) {
    const int*   edge_rows = (const int*)d_in[0];
    const int*   edge_cols = (const int*)d_in[1];
    const float* edge_vals = (const float*)d_in[2];
    const float* x         = (const float*)d_in[3];
    const float* H         = (const float*)d_in[4];
    float*       out       = (float*)d_out;

    // workspace layout (all offsets 8B-aligned)
    const size_t feat = (size_t)NN * FD;                 // 12.8M floats
    float* T2      = (float*)d_ws;                       // 51.2 MB
    float* V       = T2 + feat;                          // 51.2 MB
    int2*  pack    = (int2*)(V + feat);                  // 25.6 MB
    int*   counts  = (int*)(pack + NE);                  // 400 KB
    int*   row_ptr = counts + NN;                        // 400 KB
    int*   cursor  = row_ptr + NN + 1;                   // 400 KB
    const size_t need = (size_t)(cursor + NN + 1 - (int*)d_ws) * sizeof(int);

    const int gemm_blocks = (NN + 127) / 128;
    gemm3_kernel<<<gemm_blocks, 256, 0, stream>>>(x, H, out, V, T2);

    if (ws_size >= need) {
        // --- CSR build (reused by both SpMMs) ---
        zero_counts<<<(NN + 255) / 256, 256, 0, stream>>>(counts);
        hist_kernel<<<4096, 256, 0, stream>>>(edge_rows, counts);
        scan_kernel<<<1, 1024, 0, stream>>>(counts, row_ptr, cursor);
        scatter_kernel<<<4096, 256, 0, stream>>>(edge_rows, edge_cols, edge_vals,
                                                 cursor, pack);
        // --- V += A @ T2 ; OUT += A @ V ---
        const int spmm_blocks = (NN * 64 + 255) / 256;   // 4 rows / block
        spmm_csr<<<spmm_blocks, 256, 0, stream>>>(row_ptr, pack, T2, V);
        spmm_csr<<<spmm_blocks, 256, 0, stream>>>(row_ptr, pack, V, out);
    } else {
        spmm_atomic<<<16384, 256, 0, stream>>>(edge_rows, edge_cols, edge_vals, T2, V);
        spmm_atomic<<<16384, 256, 0, stream>>>(edge_rows, edge_cols, edge_vals, V, out);
    }
}

// Round 3
// 906.466 us; speedup vs baseline: 12.1222x; 1.5006x over previous
//
#include <hip/hip_runtime.h>

#define NN 100000
#define NE 3200000
#define FD 128

// ---------------- bf16 helpers (manual, RNE) ----------------
__device__ inline unsigned int f2bf_bits(float x) {
    unsigned int u = __float_as_uint(x);
    unsigned int r = (u + 0x7fffu + ((u >> 16) & 1u)) >> 16;   // round NE
    return r;
}
__device__ inline float bf_lo(unsigned int u) {   // low ushort -> float
    return __uint_as_float(u << 16);
}
__device__ inline float bf_hi(unsigned int u) {   // high ushort -> float
    return __uint_as_float(u & 0xffff0000u);
}

// ---------------------------------------------------------------------------
// Fused triple GEMM:  OUT = X@H0 (f32), V = X@H1 (f32), T2 = X@H2 (bf16)
// X tile staged in LDS (67.6KB -> 2 blocks/CU); H read straight from L1/L2
// (all blocks share the same 192KB H, broadcast-friendly).
// ---------------------------------------------------------------------------
__global__ __launch_bounds__(256, 2)
void gemm3_kernel(const float* __restrict__ X, const float* __restrict__ H,
                  float* __restrict__ OUT, float* __restrict__ V,
                  unsigned short* __restrict__ T2bf) {
    __shared__ float Xs[128][132];
    const int tid  = threadIdx.x;
    const int row0 = blockIdx.x * 128;

    for (int it = 0; it < 16; ++it) {
        int idx = it * 1024 + tid * 4;
        int r = idx >> 7, c = idx & 127;
        int gr = row0 + r;
        float4 v = make_float4(0.f, 0.f, 0.f, 0.f);
        if (gr < NN) v = *reinterpret_cast<const float4*>(X + gr * FD + c);
        *reinterpret_cast<float4*>(&Xs[r][c]) = v;
    }
    __syncthreads();

    const int tx = tid & 15;
    const int ty = tid >> 4;

    #pragma unroll
    for (int k = 0; k < 3; ++k) {
        const float* Hk = H + k * (FD * FD);
        float acc[8][8];
        #pragma unroll
        for (int i = 0; i < 8; ++i)
            #pragma unroll
            for (int j = 0; j < 8; ++j) acc[i][j] = 0.f;

        for (int kk = 0; kk < FD; kk += 4) {
            float4 xq[8];
            #pragma unroll
            for (int i = 0; i < 8; ++i)
                xq[i] = *reinterpret_cast<const float4*>(&Xs[ty + 16 * i][kk]);
            #pragma unroll
            for (int s = 0; s < 4; ++s) {
                float4 h0 = *reinterpret_cast<const float4*>(Hk + (kk + s) * FD + tx * 4);
                float4 h1 = *reinterpret_cast<const float4*>(Hk + (kk + s) * FD + 64 + tx * 4);
                #pragma unroll
                for (int i = 0; i < 8; ++i) {
                    float xv = (s == 0) ? xq[i].x : (s == 1) ? xq[i].y
                             : (s == 2) ? xq[i].z : xq[i].w;
                    acc[i][0] += xv * h0.x; acc[i][1] += xv * h0.y;
                    acc[i][2] += xv * h0.z; acc[i][3] += xv * h0.w;
                    acc[i][4] += xv * h1.x; acc[i][5] += xv * h1.y;
                    acc[i][6] += xv * h1.z; acc[i][7] += xv * h1.w;
                }
            }
        }

        if (k < 2) {
            float* dst = k ? V : OUT;
            #pragma unroll
            for (int i = 0; i < 8; ++i) {
                int gr = row0 + ty + 16 * i;
                if (gr < NN) {
                    float4 a = make_float4(acc[i][0], acc[i][1], acc[i][2], acc[i][3]);
                    float4 b = make_float4(acc[i][4], acc[i][5], acc[i][6], acc[i][7]);
                    *reinterpret_cast<float4*>(dst + (size_t)gr * FD + tx * 4)      = a;
                    *reinterpret_cast<float4*>(dst + (size_t)gr * FD + 64 + tx * 4) = b;
                }
            }
        } else {
            #pragma unroll
            for (int i = 0; i < 8; ++i) {
                int gr = row0 + ty + 16 * i;
                if (gr < NN) {
                    unsigned int w0 = f2bf_bits(acc[i][0]) | (f2bf_bits(acc[i][1]) << 16);
                    unsigned int w1 = f2bf_bits(acc[i][2]) | (f2bf_bits(acc[i][3]) << 16);
                    unsigned int w2 = f2bf_bits(acc[i][4]) | (f2bf_bits(acc[i][5]) << 16);
                    unsigned int w3 = f2bf_bits(acc[i][6]) | (f2bf_bits(acc[i][7]) << 16);
                    uint2 a = make_uint2(w0, w1), b = make_uint2(w2, w3);
                    *reinterpret_cast<uint2*>(T2bf + (size_t)gr * FD + tx * 4)      = a;
                    *reinterpret_cast<uint2*>(T2bf + (size_t)gr * FD + 64 + tx * 4) = b;
                }
            }
        }
    }
}

// ---------------------------------------------------------------------------
// CSR build: zero -> histogram -> hierarchical scan (3 kernels) -> scatter
// ---------------------------------------------------------------------------
__global__ __launch_bounds__(256)
void zero_counts(int* __restrict__ counts) {
    int i = blockIdx.x * blockDim.x + threadIdx.x;
    if (i < NN) counts[i] = 0;
}

__global__ __launch_bounds__(256)
void hist_kernel(const int* __restrict__ rows, int* __restrict__ counts) {
    int stride = gridDim.x * blockDim.x;
    for (int e = blockIdx.x * blockDim.x + threadIdx.x; e < NE; e += stride)
        atomicAdd(&counts[rows[e]], 1);
}

__global__ __launch_bounds__(256)
void scan_partial(const int* __restrict__ counts, int* __restrict__ bsum) {
    __shared__ int s[256];
    int i = blockIdx.x * 256 + threadIdx.x;
    int v = (i < NN) ? counts[i] : 0;
    s[threadIdx.x] = v;
    __syncthreads();
    for (int off = 128; off; off >>= 1) {
        if (threadIdx.x < off) s[threadIdx.x] += s[threadIdx.x + off];
        __syncthreads();
    }
    if (threadIdx.x == 0) bsum[blockIdx.x] = s[0];
}

__global__ __launch_bounds__(512)
void scan_tops(const int* __restrict__ bsum, int* __restrict__ boff, int nb) {
    __shared__ int s[512];
    int tid = threadIdx.x;
    int v = (tid < nb) ? bsum[tid] : 0;
    s[tid] = v;
    __syncthreads();
    for (int off = 1; off < 512; off <<= 1) {
        int t = (tid >= off) ? s[tid - off] : 0;
        __syncthreads();
        s[tid] += t;
        __syncthreads();
    }
    if (tid < nb) boff[tid] = s[tid] - v;   // exclusive
}

__global__ __launch_bounds__(256)
void scan_final(const int* __restrict__ counts, const int* __restrict__ boff,
                int* __restrict__ row_ptr, int* __restrict__ cursor) {
    __shared__ int s[256];
    int tid = threadIdx.x;
    int i = blockIdx.x * 256 + tid;
    int v = (i < NN) ? counts[i] : 0;
    s[tid] = v;
    __syncthreads();
    for (int off = 1; off < 256; off <<= 1) {
        int t = (tid >= off) ? s[tid - off] : 0;
        __syncthreads();
        s[tid] += t;
        __syncthreads();
    }
    int excl = s[tid] - v + boff[blockIdx.x];
    if (i < NN) {
        row_ptr[i] = excl;
        cursor[i]  = excl;
        if (i == NN - 1) row_ptr[NN] = excl + v;
    }
}

__global__ __launch_bounds__(256)
void scatter_kernel(const int* __restrict__ rows, const int* __restrict__ cols,
                    const float* __restrict__ vals, int* __restrict__ cursor,
                    int2* __restrict__ pack) {
    int stride = gridDim.x * blockDim.x;
    for (int e = blockIdx.x * blockDim.x + threadIdx.x; e < NE; e += stride) {
        int r   = rows[e];
        int pos = atomicAdd(&cursor[r], 1);
        pack[pos] = make_int2(cols[e], __float_as_int(vals[e]));
    }
}

// ---------------------------------------------------------------------------
// SpMM (CSR, bf16 gathers, fp32 accumulate). One wave per dest row, lane owns
// 2 features (one uint = 2 bf16). Unroll-4 for memory-level parallelism.
//   spmm_bf_bf : dst_bf[row] = init_f32[row] + sum val*src_bf[col]   (spmm 1)
//   spmm_bf_f32: dst_f32[row] +=              sum val*src_bf[col]    (spmm 2)
// ---------------------------------------------------------------------------
#define SPMM_BODY(ACC_INIT, STORE)                                             \
    const int lane = threadIdx.x & 63;                                         \
    const int row  = (blockIdx.x * blockDim.x + threadIdx.x) >> 6;             \
    if (row >= NN) return;                                                     \
    const int beg = row_ptr[row], end = row_ptr[row + 1];                      \
    float2 acc = ACC_INIT;                                                     \
    int e = beg;                                                               \
    for (; e + 3 < end; e += 4) {                                              \
        int2 p0 = pack[e], p1 = pack[e+1], p2 = pack[e+2], p3 = pack[e+3];     \
        unsigned int g0 = *reinterpret_cast<const unsigned int*>(src + (size_t)p0.x * FD + lane * 2); \
        unsigned int g1 = *reinterpret_cast<const unsigned int*>(src + (size_t)p1.x * FD + lane * 2); \
        unsigned int g2 = *reinterpret_cast<const unsigned int*>(src + (size_t)p2.x * FD + lane * 2); \
        unsigned int g3 = *reinterpret_cast<const unsigned int*>(src + (size_t)p3.x * FD + lane * 2); \
        float v0 = __int_as_float(p0.y), v1 = __int_as_float(p1.y);            \
        float v2 = __int_as_float(p2.y), v3 = __int_as_float(p3.y);            \
        acc.x += v0 * bf_lo(g0) + v1 * bf_lo(g1) + v2 * bf_lo(g2) + v3 * bf_lo(g3); \
        acc.y += v0 * bf_hi(g0) + v1 * bf_hi(g1) + v2 * bf_hi(g2) + v3 * bf_hi(g3); \
    }                                                                          \
    for (; e < end; ++e) {                                                     \
        int2 p = pack[e];                                                      \
        unsigned int g = *reinterpret_cast<const unsigned int*>(src + (size_t)p.x * FD + lane * 2); \
        float v = __int_as_float(p.y);                                         \
        acc.x += v * bf_lo(g);                                                 \
        acc.y += v * bf_hi(g);                                                 \
    }                                                                          \
    STORE

__global__ __launch_bounds__(256)
void spmm_bf_bf(const int* __restrict__ row_ptr, const int2* __restrict__ pack,
                const unsigned short* __restrict__ src,
                const float* __restrict__ init, unsigned short* __restrict__ dst) {
    SPMM_BODY(
        (*reinterpret_cast<const float2*>(init + (size_t)row * FD + lane * 2)),
        {
            unsigned int w = f2bf_bits(acc.x) | (f2bf_bits(acc.y) << 16);
            *reinterpret_cast<unsigned int*>(dst + (size_t)row * FD + lane * 2) = w;
        })
}

__global__ __launch_bounds__(256)
void spmm_bf_f32(const int* __restrict__ row_ptr, const int2* __restrict__ pack,
                 const unsigned short* __restrict__ src, float* __restrict__ dst) {
    SPMM_BODY(
        (*reinterpret_cast<const float2*>(dst + (size_t)row * FD + lane * 2)),
        {
            *reinterpret_cast<float2*>(dst + (size_t)row * FD + lane * 2) = acc;
        })
}

extern "C" void kernel_launch(void* const* d_in, const int* in_sizes, int n_in,
                              void* d_out, int out_size, void* d_ws, size_t ws_size,
                              hipStream_t stream) {
    const int*   edge_rows = (const int*)d_in[0];
    const int*   edge_cols = (const int*)d_in[1];
    const float* edge_vals = (const float*)d_in[2];
    const float* x         = (const float*)d_in[3];
    const float* H         = (const float*)d_in[4];
    float*       out       = (float*)d_out;

    // workspace layout
    const size_t feat = (size_t)NN * FD;
    float*          V_f32 = (float*)d_ws;                    // 51.2 MB
    unsigned short* T2bf  = (unsigned short*)(V_f32 + feat); // 25.6 MB
    unsigned short* Vbf   = T2bf + feat;                     // 25.6 MB
    int2*           pack  = (int2*)(Vbf + feat);             // 25.6 MB
    int* counts  = (int*)(pack + NE);
    int* row_ptr = counts + NN;
    int* cursor  = row_ptr + NN + 1;
    int* bsum    = cursor + NN;
    int* boff    = bsum + 512;

    const int NB = (NN + 255) / 256;   // 391

    // OUT = X@H0, V_f32 = X@H1, T2bf = bf16(X@H2)
    gemm3_kernel<<<(NN + 127) / 128, 256, 0, stream>>>(x, H, out, V_f32, T2bf);

    // CSR build
    zero_counts<<<NB, 256, 0, stream>>>(counts);
    hist_kernel<<<4096, 256, 0, stream>>>(edge_rows, counts);
    scan_partial<<<NB, 256, 0, stream>>>(counts, bsum);
    scan_tops<<<1, 512, 0, stream>>>(bsum, boff, NB);
    scan_final<<<NB, 256, 0, stream>>>(counts, boff, row_ptr, cursor);
    scatter_kernel<<<4096, 256, 0, stream>>>(edge_rows, edge_cols, edge_vals,
                                             cursor, pack);

    // Vbf = bf16(V_f32 + A@T2bf) ; OUT += A@Vbf
    const int spmm_blocks = (NN * 64 + 255) / 256;   // 25000
    spmm_bf_bf <<<spmm_blocks, 256, 0, stream>>>(row_ptr, pack, T2bf, V_f32, Vbf);
    spmm_bf_f32<<<spmm_blocks, 256, 0, stream>>>(row_ptr, pack, Vbf, out);
}

// Round 4
// 734.114 us; speedup vs baseline: 14.9682x; 1.2348x over previous
//
#include <hip/hip_runtime.h>

#define NN 100000
#define NE 3200000
#define FD 128
#define NBUK 782                 // ceil(NN/128), rows per bucket = 128
#define NSEG (NBUK * 8)          // 6256 (bucket-major, group-minor)
#define NBIN 1024                // binning blocks; NE % NBIN == 0
#define CHUNK (NE / NBIN)        // 3125 edges per binning block
#define MAXB 5120                // LDS stage capacity per bucket (λ=4096, 16σ margin)

// ---------------- bf16 helpers (manual, RNE) ----------------
__device__ inline unsigned int f2bf_bits(float x) {
    unsigned int u = __float_as_uint(x);
    return (u + 0x7fffu + ((u >> 16) & 1u)) >> 16;
}
__device__ inline float bf_lo(unsigned int u) { return __uint_as_float(u << 16); }
__device__ inline float bf_hi(unsigned int u) { return __uint_as_float(u & 0xffff0000u); }

// ---------------------------------------------------------------------------
// Fused triple GEMM:  OUT = X@H0 (f32), V = X@H1 (f32), T2 = X@H2 (bf16)
// ---------------------------------------------------------------------------
__global__ __launch_bounds__(256, 2)
void gemm3_kernel(const float* __restrict__ X, const float* __restrict__ H,
                  float* __restrict__ OUT, float* __restrict__ V,
                  unsigned short* __restrict__ T2bf) {
    __shared__ float Xs[128][132];
    const int tid  = threadIdx.x;
    const int row0 = blockIdx.x * 128;

    for (int it = 0; it < 16; ++it) {
        int idx = it * 1024 + tid * 4;
        int r = idx >> 7, c = idx & 127;
        int gr = row0 + r;
        float4 v = make_float4(0.f, 0.f, 0.f, 0.f);
        if (gr < NN) v = *reinterpret_cast<const float4*>(X + gr * FD + c);
        *reinterpret_cast<float4*>(&Xs[r][c]) = v;
    }
    __syncthreads();

    const int tx = tid & 15;
    const int ty = tid >> 4;

    #pragma unroll
    for (int k = 0; k < 3; ++k) {
        const float* Hk = H + k * (FD * FD);
        float acc[8][8];
        #pragma unroll
        for (int i = 0; i < 8; ++i)
            #pragma unroll
            for (int j = 0; j < 8; ++j) acc[i][j] = 0.f;

        for (int kk = 0; kk < FD; kk += 4) {
            float4 xq[8];
            #pragma unroll
            for (int i = 0; i < 8; ++i)
                xq[i] = *reinterpret_cast<const float4*>(&Xs[ty + 16 * i][kk]);
            #pragma unroll
            for (int s = 0; s < 4; ++s) {
                float4 h0 = *reinterpret_cast<const float4*>(Hk + (kk + s) * FD + tx * 4);
                float4 h1 = *reinterpret_cast<const float4*>(Hk + (kk + s) * FD + 64 + tx * 4);
                #pragma unroll
                for (int i = 0; i < 8; ++i) {
                    float xv = (s == 0) ? xq[i].x : (s == 1) ? xq[i].y
                             : (s == 2) ? xq[i].z : xq[i].w;
                    acc[i][0] += xv * h0.x; acc[i][1] += xv * h0.y;
                    acc[i][2] += xv * h0.z; acc[i][3] += xv * h0.w;
                    acc[i][4] += xv * h1.x; acc[i][5] += xv * h1.y;
                    acc[i][6] += xv * h1.z; acc[i][7] += xv * h1.w;
                }
            }
        }

        if (k < 2) {
            float* dst = k ? V : OUT;
            #pragma unroll
            for (int i = 0; i < 8; ++i) {
                int gr = row0 + ty + 16 * i;
                if (gr < NN) {
                    float4 a = make_float4(acc[i][0], acc[i][1], acc[i][2], acc[i][3]);
                    float4 b = make_float4(acc[i][4], acc[i][5], acc[i][6], acc[i][7]);
                    *reinterpret_cast<float4*>(dst + (size_t)gr * FD + tx * 4)      = a;
                    *reinterpret_cast<float4*>(dst + (size_t)gr * FD + 64 + tx * 4) = b;
                }
            }
        } else {
            #pragma unroll
            for (int i = 0; i < 8; ++i) {
                int gr = row0 + ty + 16 * i;
                if (gr < NN) {
                    unsigned int w0 = f2bf_bits(acc[i][0]) | (f2bf_bits(acc[i][1]) << 16);
                    unsigned int w1 = f2bf_bits(acc[i][2]) | (f2bf_bits(acc[i][3]) << 16);
                    unsigned int w2 = f2bf_bits(acc[i][4]) | (f2bf_bits(acc[i][5]) << 16);
                    unsigned int w3 = f2bf_bits(acc[i][6]) | (f2bf_bits(acc[i][7]) << 16);
                    *reinterpret_cast<uint2*>(T2bf + (size_t)gr * FD + tx * 4)      = make_uint2(w0, w1);
                    *reinterpret_cast<uint2*>(T2bf + (size_t)gr * FD + 64 + tx * 4) = make_uint2(w2, w3);
                }
            }
        }
    }
}

// ---------------------------------------------------------------------------
// Bucketed CSR build.
// g = blockIdx&7 segregates write streams by (presumed round-robin) XCD so
// cacheline writebacks combine in the local L2. g is only a LABEL: hist and
// scatter use the identical block->edge chunking, so sizing is exact even if
// the dispatcher maps blocks differently (then we only lose the combining).
// ---------------------------------------------------------------------------
__global__ __launch_bounds__(256)
void zero_counts(int* __restrict__ counts) {
    int i = blockIdx.x * 256 + threadIdx.x;
    if (i < NSEG) counts[i] = 0;
}

__global__ __launch_bounds__(256)
void bucket_hist(const int* __restrict__ rows, int* __restrict__ counts) {
    __shared__ int lh[NBUK];
    for (int i = threadIdx.x; i < NBUK; i += 256) lh[i] = 0;
    __syncthreads();
    const int beg = blockIdx.x * CHUNK, end = beg + CHUNK;
    for (int e = beg + threadIdx.x; e < end; e += 256)
        atomicAdd(&lh[rows[e] >> 7], 1);
    __syncthreads();
    const int g = blockIdx.x & 7;
    for (int b = threadIdx.x; b < NBUK; b += 256)
        if (lh[b]) atomicAdd(&counts[b * 8 + g], lh[b]);
}

__global__ __launch_bounds__(1024)
void scan_segs(const int* __restrict__ counts, int* __restrict__ cursor,
               int* __restrict__ bucket_ptr) {
    __shared__ int s[1024];
    const int tid = threadIdx.x;
    const int per = (NSEG + 1023) / 1024;   // 7
    const int base = tid * per;
    int sum = 0;
    for (int i = 0; i < per; ++i) {
        int idx = base + i;
        if (idx < NSEG) sum += counts[idx];
    }
    s[tid] = sum;
    __syncthreads();
    for (int off = 1; off < 1024; off <<= 1) {
        int t = (tid >= off) ? s[tid - off] : 0;
        __syncthreads();
        s[tid] += t;
        __syncthreads();
    }
    int run = s[tid] - sum;                  // exclusive
    for (int i = 0; i < per; ++i) {
        int idx = base + i;
        if (idx < NSEG) {
            cursor[idx] = run;
            if ((idx & 7) == 0) bucket_ptr[idx >> 3] = run;
            run += counts[idx];
        }
    }
    if (tid == 1023) bucket_ptr[NBUK] = NE;
}

// records: x = (rowlow7 << 17) | col17 ; y = val bits
__global__ __launch_bounds__(256)
void bin_scatter(const int* __restrict__ rows, const int* __restrict__ cols,
                 const float* __restrict__ vals, int* __restrict__ cursor,
                 uint2* __restrict__ recs) {
    const int beg = blockIdx.x * CHUNK, end = beg + CHUNK;
    const int g = blockIdx.x & 7;
    for (int e = beg + threadIdx.x; e < end; e += 256) {
        int r = rows[e];
        int b = r >> 7;
        int pos = atomicAdd(&cursor[b * 8 + g], 1);
        recs[pos] = make_uint2(((unsigned)(r & 127) << 17) | (unsigned)cols[e],
                               __float_as_uint(vals[e]));
    }
}

// One block per bucket: stage records in LDS, local hist+scan over 128 rows,
// write back row-sorted IN PLACE, emit row_ptr.
__global__ __launch_bounds__(256)
void bucket_csr(uint2* __restrict__ recs, const int* __restrict__ bucket_ptr,
                int* __restrict__ row_ptr) {
    __shared__ uint2 stage[MAXB];
    __shared__ int lh[128];
    __shared__ int lsc[128];
    const int b = blockIdx.x, tid = threadIdx.x;
    const int beg = bucket_ptr[b], end = bucket_ptr[b + 1];
    const int n = end - beg;

    if (tid < 128) lh[tid] = 0;
    __syncthreads();
    for (int i = tid; i < n; i += 256) {
        uint2 r = recs[beg + i];
        stage[i] = r;
        atomicAdd(&lh[r.x >> 17], 1);
    }
    __syncthreads();
    // inclusive Hillis-Steele over 128 (unconditional barriers)
    int v = (tid < 128) ? lh[tid] : 0;
    if (tid < 128) lsc[tid] = v;
    __syncthreads();
    for (int off = 1; off < 128; off <<= 1) {
        int t = 0;
        if (tid < 128 && tid >= off) t = lsc[tid - off];
        __syncthreads();
        if (tid < 128) lsc[tid] += t;
        __syncthreads();
    }
    if (tid < 128) {
        int excl = lsc[tid] - v;
        int gr = b * 128 + tid;
        if (gr <= NN) row_ptr[gr] = beg + excl;   // gr==NN -> row_ptr[NN]=NE
        lh[tid] = excl;                            // reuse as local cursor
    }
    __syncthreads();
    for (int i = tid; i < n; i += 256) {
        uint2 r = stage[i];
        int pos = atomicAdd(&lh[r.x >> 17], 1);
        recs[beg + pos] = r;
    }
}

// ---------------------------------------------------------------------------
// SpMM (CSR, bf16 gathers, fp32 accumulate). One wave per dest row, lane owns
// 2 features. Unroll-8 for memory-level parallelism. col = rec.x & 0x1FFFF.
// ---------------------------------------------------------------------------
#define SPMM_BODY(ACC_INIT, STORE)                                             \
    const int lane = threadIdx.x & 63;                                         \
    const int row  = (blockIdx.x * blockDim.x + threadIdx.x) >> 6;             \
    if (row >= NN) return;                                                     \
    const int beg = row_ptr[row], end = row_ptr[row + 1];                      \
    float2 acc = ACC_INIT;                                                     \
    int e = beg;                                                               \
    for (; e + 7 < end; e += 8) {                                              \
        uint2 p[8];                                                            \
        unsigned int g[8];                                                     \
        _Pragma("unroll")                                                      \
        for (int u = 0; u < 8; ++u) p[u] = recs[e + u];                        \
        _Pragma("unroll")                                                      \
        for (int u = 0; u < 8; ++u)                                            \
            g[u] = *reinterpret_cast<const unsigned int*>(                     \
                src + (size_t)(p[u].x & 0x1FFFF) * FD + lane * 2);             \
        _Pragma("unroll")                                                      \
        for (int u = 0; u < 8; ++u) {                                          \
            float v = __uint_as_float(p[u].y);                                 \
            acc.x += v * bf_lo(g[u]);                                          \
            acc.y += v * bf_hi(g[u]);                                          \
        }                                                                      \
    }                                                                          \
    for (; e < end; ++e) {                                                     \
        uint2 p = recs[e];                                                     \
        unsigned int g = *reinterpret_cast<const unsigned int*>(               \
            src + (size_t)(p.x & 0x1FFFF) * FD + lane * 2);                    \
        float v = __uint_as_float(p.y);                                        \
        acc.x += v * bf_lo(g);                                                 \
        acc.y += v * bf_hi(g);                                                 \
    }                                                                          \
    STORE

__global__ __launch_bounds__(256)
void spmm_bf_bf(const int* __restrict__ row_ptr, const uint2* __restrict__ recs,
                const unsigned short* __restrict__ src,
                const float* __restrict__ init, unsigned short* __restrict__ dst) {
    SPMM_BODY(
        (*reinterpret_cast<const float2*>(init + (size_t)row * FD + lane * 2)),
        {
            unsigned int w = f2bf_bits(acc.x) | (f2bf_bits(acc.y) << 16);
            *reinterpret_cast<unsigned int*>(dst + (size_t)row * FD + lane * 2) = w;
        })
}

__global__ __launch_bounds__(256)
void spmm_bf_f32(const int* __restrict__ row_ptr, const uint2* __restrict__ recs,
                 const unsigned short* __restrict__ src, float* __restrict__ dst) {
    SPMM_BODY(
        (*reinterpret_cast<const float2*>(dst + (size_t)row * FD + lane * 2)),
        {
            *reinterpret_cast<float2*>(dst + (size_t)row * FD + lane * 2) = acc;
        })
}

extern "C" void kernel_launch(void* const* d_in, const int* in_sizes, int n_in,
                              void* d_out, int out_size, void* d_ws, size_t ws_size,
                              hipStream_t stream) {
    const int*   edge_rows = (const int*)d_in[0];
    const int*   edge_cols = (const int*)d_in[1];
    const float* edge_vals = (const float*)d_in[2];
    const float* x         = (const float*)d_in[3];
    const float* H         = (const float*)d_in[4];
    float*       out       = (float*)d_out;

    // workspace layout (~128.5 MB total)
    const size_t feat = (size_t)NN * FD;
    float*          V_f32 = (float*)d_ws;                      // 51.2 MB
    unsigned short* T2bf  = (unsigned short*)(V_f32 + feat);   // 25.6 MB
    unsigned short* Vbf   = T2bf + feat;                       // 25.6 MB
    uint2*          recs  = (uint2*)(Vbf + feat);              // 25.6 MB
    int* counts     = (int*)(recs + NE);                       // 25 KB
    int* cursor     = counts + NSEG;                           // 25 KB
    int* row_ptr    = cursor + NSEG;                           // 400 KB
    int* bucket_ptr = row_ptr + NN + 1;                        // 3.1 KB

    // OUT = X@H0, V_f32 = X@H1, T2bf = bf16(X@H2)
    gemm3_kernel<<<(NN + 127) / 128, 256, 0, stream>>>(x, H, out, V_f32, T2bf);

    // Bucketed CSR build
    zero_counts<<<(NSEG + 255) / 256, 256, 0, stream>>>(counts);
    bucket_hist<<<NBIN, 256, 0, stream>>>(edge_rows, counts);
    scan_segs<<<1, 1024, 0, stream>>>(counts, cursor, bucket_ptr);
    bin_scatter<<<NBIN, 256, 0, stream>>>(edge_rows, edge_cols, edge_vals,
                                          cursor, recs);
    bucket_csr<<<NBUK, 256, 0, stream>>>(recs, bucket_ptr, row_ptr);

    // Vbf = bf16(V_f32 + A@T2bf) ; OUT += A@Vbf
    const int spmm_blocks = (NN * 64 + 255) / 256;   // 25000
    spmm_bf_bf <<<spmm_blocks, 256, 0, stream>>>(row_ptr, recs, T2bf, V_f32, Vbf);
    spmm_bf_f32<<<spmm_blocks, 256, 0, stream>>>(row_ptr, recs, Vbf, out);
}